// Round 1
// baseline (241.354 us; speedup 1.0000x reference)
//
#include <hip/hip_runtime.h>
#include <math.h>

#define NND 20000
#define NE  320000
#define NF  128
#define NRBF 20

static constexpr float FCUT = 5.0f;
static constexpr float FEPS = 1e-8f;
static constexpr float PIC  = 3.14159265358979323846f / 5.0f;  // pi / CUTOFF

// ---------------- histogram of destination nodes ----------------
__global__ __launch_bounds__(256) void hist_k(const float* __restrict__ r,
                                              int* __restrict__ counts) {
    int e = blockIdx.x * 256 + threadIdx.x;
    if (e < NE) {
        int j = (int)r[(size_t)e * 5 + 1];
        atomicAdd(&counts[j], 1);
    }
}

// ---------------- exclusive scan (20000 elems, 1 block) ----------------
// counts_cursor holds counts on entry; on exit holds the exclusive offsets
// (used as the scatter cursor). offsets[] additionally gets offsets[NND]=E.
__global__ __launch_bounds__(1024) void scan_k(int* counts_cursor,
                                               int* offsets) {
    __shared__ int part[1024];
    const int CH = 20;  // 1024*20 = 20480 >= 20000
    int t = threadIdx.x;
    int base = t * CH;
    int loc[CH];
    int sum = 0;
#pragma unroll
    for (int i = 0; i < CH; i++) {
        int idx = base + i;
        int c = (idx < NND) ? counts_cursor[idx] : 0;
        loc[i] = sum;
        sum += c;
    }
    part[t] = sum;
    __syncthreads();
    for (int off = 1; off < 1024; off <<= 1) {
        int val = (t >= off) ? part[t - off] : 0;
        __syncthreads();
        part[t] += val;
        __syncthreads();
    }
    int excl = part[t] - sum;
#pragma unroll
    for (int i = 0; i < CH; i++) {
        int idx = base + i;
        if (idx < NND) {
            int o = excl + loc[i];
            offsets[idx] = o;
            counts_cursor[idx] = o;
        }
    }
    if (t == 1023) offsets[NND] = part[1023];
}

// ---------------- scatter edges into CSR order, precompute dir/norm ----------------
__global__ __launch_bounds__(256) void scatter_k(const float* __restrict__ r,
                                                 int* __restrict__ cursor,
                                                 float4* __restrict__ payload) {
    int e = blockIdx.x * 256 + threadIdx.x;
    if (e >= NE) return;
    const float* re = r + (size_t)e * 5;
    int j = (int)re[1];
    float x = re[2], y = re[3], z = re[4];
    float nrm = sqrtf(x * x + y * y + z * z);
    float inv = 1.0f / ((nrm + FEPS) * (nrm + FEPS));
    int pos = atomicAdd(&cursor[j], 1);
    payload[pos] = make_float4(x * inv, y * inv, z * inv, nrm);
}

// ---------------- h = silu(s @ W1 + b1) ----------------
// 64-node tile per block, 256 threads, 4x8 register tile each.
__global__ __launch_bounds__(256) void gemm_h_k(const float* __restrict__ s,
                                                const float* __restrict__ W1,
                                                const float* __restrict__ b1,
                                                float* __restrict__ h) {
    __shared__ float sT[128][68];  // transposed tile, padded
    int node0 = blockIdx.x * 64;
    int tid = threadIdx.x;
    for (int i = tid; i < 64 * 128; i += 256) {
        int n = i >> 7, k = i & 127;
        int node = node0 + n;
        sT[k][n] = (node < NND) ? s[(size_t)node * NF + k] : 0.0f;
    }
    __syncthreads();
    int tf = tid & 15, tn = tid >> 4;
    float acc[4][8];
#pragma unroll
    for (int i = 0; i < 4; i++)
#pragma unroll
        for (int j2 = 0; j2 < 8; j2++) acc[i][j2] = 0.0f;
    const float* Wp = W1 + tf * 8;
    for (int k = 0; k < 128; k++) {
        float4 bA = *(const float4*)(Wp + (size_t)k * NF);
        float4 bB = *(const float4*)(Wp + (size_t)k * NF + 4);
        float4 a = *(const float4*)(&sT[k][tn * 4]);
        float av[4] = {a.x, a.y, a.z, a.w};
        float bv[8] = {bA.x, bA.y, bA.z, bA.w, bB.x, bB.y, bB.z, bB.w};
#pragma unroll
        for (int i = 0; i < 4; i++)
#pragma unroll
            for (int j2 = 0; j2 < 8; j2++)
                acc[i][j2] = fmaf(av[i], bv[j2], acc[i][j2]);
    }
#pragma unroll
    for (int i = 0; i < 4; i++) {
        int node = node0 + tn * 4 + i;
        if (node >= NND) continue;
#pragma unroll
        for (int j2 = 0; j2 < 8; j2++) {
            int f = tf * 8 + j2;
            float x = acc[i][j2] + b1[f];
            float sg = 1.0f / (1.0f + __expf(-x));
            h[(size_t)node * NF + f] = x * sg;
        }
    }
}

// ---------------- phi = h @ W2 + b2  (384 cols in 3 chunks of 128) ----------------
__global__ __launch_bounds__(256) void gemm_phi_k(const float* __restrict__ h,
                                                  const float* __restrict__ W2,
                                                  const float* __restrict__ b2,
                                                  float* __restrict__ phi) {
    __shared__ float hT[128][68];
    int node0 = blockIdx.x * 64;
    int c = blockIdx.y;  // 0..2
    int tid = threadIdx.x;
    for (int i = tid; i < 64 * 128; i += 256) {
        int n = i >> 7, k = i & 127;
        int node = node0 + n;
        hT[k][n] = (node < NND) ? h[(size_t)node * NF + k] : 0.0f;
    }
    __syncthreads();
    int tf = tid & 15, tn = tid >> 4;
    float acc[4][8];
#pragma unroll
    for (int i = 0; i < 4; i++)
#pragma unroll
        for (int j2 = 0; j2 < 8; j2++) acc[i][j2] = 0.0f;
    const float* Wp = W2 + c * NF + tf * 8;
    for (int k = 0; k < 128; k++) {
        float4 bA = *(const float4*)(Wp + (size_t)k * 384);
        float4 bB = *(const float4*)(Wp + (size_t)k * 384 + 4);
        float4 a = *(const float4*)(&hT[k][tn * 4]);
        float av[4] = {a.x, a.y, a.z, a.w};
        float bv[8] = {bA.x, bA.y, bA.z, bA.w, bB.x, bB.y, bB.z, bB.w};
#pragma unroll
        for (int i = 0; i < 4; i++)
#pragma unroll
            for (int j2 = 0; j2 < 8; j2++)
                acc[i][j2] = fmaf(av[i], bv[j2], acc[i][j2]);
    }
#pragma unroll
    for (int i = 0; i < 4; i++) {
        int node = node0 + tn * 4 + i;
        if (node >= NND) continue;
#pragma unroll
        for (int j2 = 0; j2 < 8; j2++) {
            int f = c * NF + tf * 8 + j2;
            phi[(size_t)node * 384 + f] = acc[i][j2] + b2[f];
        }
    }
}

// ---------------- per-node reduction over its edges + output write ----------------
__global__ __launch_bounds__(128) void reduce_k(const int* __restrict__ offsets,
                                                const float4* __restrict__ payload,
                                                const float* __restrict__ phi,
                                                const float* __restrict__ v,
                                                const float* __restrict__ Wr,
                                                const float* __restrict__ br,
                                                float* __restrict__ dv,
                                                float* __restrict__ ds) {
    int j = blockIdx.x;
    int f = threadIdx.x;
    // hoist Wr columns f, f+128, f+256 into registers (60 VGPRs)
    float wr0[NRBF], wr1[NRBF], wr2[NRBF];
#pragma unroll
    for (int k = 0; k < NRBF; k++) {
        wr0[k] = Wr[k * 384 + f];
        wr1[k] = Wr[k * 384 + 128 + f];
        wr2[k] = Wr[k * 384 + 256 + f];
    }
    float bb0 = br[f], bb1 = br[128 + f], bb2 = br[256 + f];

    float sum1 = 0.f, sum2 = 0.f, sd0 = 0.f, sd1 = 0.f, sd2 = 0.f;
    int beg = offsets[j], end = offsets[j + 1];

    __shared__ float4 pay[16];
    __shared__ float rbfL[16][NRBF];

    for (int base = beg; base < end; base += 16) {
        int cnt = min(16, end - base);
        __syncthreads();  // protect prev iteration's LDS reads
        if (f < cnt) pay[f] = payload[base + f];
        __syncthreads();
        for (int item = f; item < cnt * NRBF; item += 128) {
            int ec = item / NRBF, k = item - ec * NRBF;
            float nrm = pay[ec].w;
            float nc = fmaxf(nrm, FEPS);
            float sv = sinf((float)(k + 1) * PIC * nc) / (nc + FEPS);
            rbfL[ec][k] = fminf(fmaxf(sv, -1.f), 1.f);
        }
        __syncthreads();
        for (int ec = 0; ec < cnt; ec++) {
            float a0 = bb0, a1 = bb1, a2 = bb2;
#pragma unroll
            for (int k = 0; k < NRBF; k++) {
                float rb = rbfL[ec][k];
                a0 = fmaf(rb, wr0[k], a0);
                a1 = fmaf(rb, wr1[k], a1);
                a2 = fmaf(rb, wr2[k], a2);
            }
            float w0 = 0.5f * (__cosf(PIC * a0) + 1.f); if (!(a0 < FCUT)) w0 = 0.f;
            float w1 = 0.5f * (__cosf(PIC * a1) + 1.f); if (!(a1 < FCUT)) w1 = 0.f;
            float w2 = 0.5f * (__cosf(PIC * a2) + 1.f); if (!(a2 < FCUT)) w2 = 0.f;
            sum1 += w0;
            sum2 += w1;
            float4 p = pay[ec];
            sd0 = fmaf(w2, p.x, sd0);
            sd1 = fmaf(w2, p.y, sd1);
            sd2 = fmaf(w2, p.z, sd2);
        }
    }

    float p1 = phi[(size_t)j * 384 + f];
    float p2 = phi[(size_t)j * 384 + 128 + f];
    float p3 = phi[(size_t)j * 384 + 256 + f];
    ds[(size_t)j * NF + f] = p2 * sum2;
    float c1 = p1 * sum1;
    size_t vb = ((size_t)j * NF + f) * 3;
    dv[vb + 0] = fmaf(v[vb + 0], c1, p3 * sd0);
    dv[vb + 1] = fmaf(v[vb + 1], c1, p3 * sd1);
    dv[vb + 2] = fmaf(v[vb + 2], c1, p3 * sd2);
}

extern "C" void kernel_launch(void* const* d_in, const int* in_sizes, int n_in,
                              void* d_out, int out_size, void* d_ws, size_t ws_size,
                              hipStream_t stream) {
    const float* v  = (const float*)d_in[0];
    const float* s  = (const float*)d_in[1];
    const float* r  = (const float*)d_in[2];
    const float* W1 = (const float*)d_in[3];
    const float* b1 = (const float*)d_in[4];
    const float* W2 = (const float*)d_in[5];
    const float* b2 = (const float*)d_in[6];
    const float* Wr = (const float*)d_in[7];
    const float* br = (const float*)d_in[8];

    float* dv = (float*)d_out;                    // NND*NF*3
    float* ds = dv + (size_t)NND * NF * 3;        // NND*NF

    char* ws = (char*)d_ws;
    // layout: offsets (N+1 ints) | cursor (N ints) | bufA (h then payload) | phi
    int* offsets = (int*)ws;                                   // 80128 B slot
    int* cursor  = (int*)(ws + 80128);                         // 80128 B slot
    float* bufA  = (float*)(ws + 160256);                      // 10,240,000 B
    float* phi   = (float*)(ws + 160256 + 10240000);           // 30,720,000 B

    // 1. CSR build: histogram -> scan -> (later) scatter
    hipMemsetAsync(cursor, 0, NND * sizeof(int), stream);
    hist_k<<<(NE + 255) / 256, 256, 0, stream>>>(r, cursor);
    scan_k<<<1, 1024, 0, stream>>>(cursor, offsets);

    // 2. node MLP: h = silu(s@W1+b1); phi = h@W2+b2   (h lives in bufA)
    int nodeBlocks = (NND + 63) / 64;  // 313
    gemm_h_k<<<nodeBlocks, 256, 0, stream>>>(s, W1, b1, bufA);
    gemm_phi_k<<<dim3(nodeBlocks, 3), 256, 0, stream>>>(bufA, W2, b2, phi);

    // 3. scatter edges into CSR order (bufA reused as payload)
    scatter_k<<<(NE + 255) / 256, 256, 0, stream>>>(r, cursor, (float4*)bufA);

    // 4. per-node reduction + outputs
    reduce_k<<<NND, 128, 0, stream>>>(offsets, (const float4*)bufA, phi, v, Wr, br, dv, ds);
}